// Round 5
// baseline (614.255 us; speedup 1.0000x reference)
//
#include <hip/hip_runtime.h>
#include <cstdint>
#include <cmath>

typedef unsigned short u16;
typedef unsigned int u32;
typedef __attribute__((ext_vector_type(8))) short bf16x8;
typedef __attribute__((ext_vector_type(4))) float f32x4;

#define TT 4096
#define DD 512
#define MM (8 * 4096)   // B*T rows

__device__ __forceinline__ float b2f(u16 v) {
    u32 u = ((u32)v) << 16;
    float f;
    __builtin_memcpy(&f, &u, 4);
    return f;
}
__device__ __forceinline__ u16 f2b(float f) {
    u32 u;
    __builtin_memcpy(&u, &f, 4);
    u32 r = (u + 0x7fffu + ((u >> 16) & 1u)) >> 16;  // RNE
    return (u16)r;
}

// Barrier WITHOUT the vmcnt/expcnt drain __syncthreads() implies.
// LDS ordering preserved via lgkmcnt(0); global ops stay in flight.
__device__ __forceinline__ void barrier_nf() {
    __asm__ volatile("s_waitcnt lgkmcnt(0)\n\ts_barrier" ::: "memory");
}

// ---------------------------------------------------------------------------
// Weight conversion: Wi,W1,W2 -> bf16 (concat), dw_w [512,1,5] -> wt [5][512]
// ---------------------------------------------------------------------------
__global__ void convert_kernel(const float* __restrict__ Wi, const float* __restrict__ W1,
                               const float* __restrict__ W2, const float* __restrict__ dw,
                               u16* __restrict__ wb, float* __restrict__ wt) {
    int i = blockIdx.x * blockDim.x + threadIdx.x;
    const int n0 = 1536 * 512, n1 = n0 + 1024 * 512, n2 = n1 + 512 * 1024;
    for (int idx = i; idx < n2; idx += gridDim.x * blockDim.x) {
        float v;
        if (idx < n0) v = Wi[idx];
        else if (idx < n1) v = W1[idx - n0];
        else v = W2[idx - n1];
        wb[idx] = f2b(v);
    }
    if (i < 5 * 512) {
        int k = i >> 9, d = i & 511;
        wt[i] = dw[d * 5 + k];
    }
}

// ---------------------------------------------------------------------------
// Fused LN1 + cell-LN: h = LN(x)*g1+b1 (stored bf16), hn = LN(h)*cg+cb (bf16)
// 1 wave per row (512 cols, 8/lane)
// ---------------------------------------------------------------------------
__global__ __launch_bounds__(256)
void ln_kernel(const float* __restrict__ x, const float* __restrict__ g1,
               const float* __restrict__ b1, const float* __restrict__ cg,
               const float* __restrict__ cb, u16* __restrict__ hb,
               u16* __restrict__ hn) {
    int wv = threadIdx.x >> 6, lane = threadIdx.x & 63;
    size_t row = (size_t)blockIdx.x * 4 + wv;
    int col = lane * 8;
    const float* xr = x + row * DD + col;
    float v[8];
    {
        float4 a = *(const float4*)xr;
        float4 b = *(const float4*)(xr + 4);
        v[0] = a.x; v[1] = a.y; v[2] = a.z; v[3] = a.w;
        v[4] = b.x; v[5] = b.y; v[6] = b.z; v[7] = b.w;
    }
    float s1 = 0.f, s2 = 0.f;
#pragma unroll
    for (int j = 0; j < 8; j++) { s1 += v[j]; s2 += v[j] * v[j]; }
#pragma unroll
    for (int off = 32; off; off >>= 1) { s1 += __shfl_xor(s1, off); s2 += __shfl_xor(s2, off); }
    float m = s1 * (1.f / DD);
    float var = s2 * (1.f / DD) - m * m;
    float rs = __builtin_amdgcn_rsqf(var + 1e-5f);

    float4 ga = *(const float4*)(g1 + col), gb = *(const float4*)(g1 + col + 4);
    float4 ba = *(const float4*)(b1 + col), bb = *(const float4*)(b1 + col + 4);
    float gv[8] = {ga.x, ga.y, ga.z, ga.w, gb.x, gb.y, gb.z, gb.w};
    float bv[8] = {ba.x, ba.y, ba.z, ba.w, bb.x, bb.y, bb.z, bb.w};
    float hv[8];
#pragma unroll
    for (int j = 0; j < 8; j++) hv[j] = (v[j] - m) * rs * gv[j] + bv[j];
    {
        union { u16 q[8]; float4 f; } H;
#pragma unroll
        for (int j = 0; j < 8; j++) H.q[j] = f2b(hv[j]);
        *(float4*)(hb + row * DD + col) = H.f;
    }
    // second LN over h (fp32 hv)
    s1 = 0.f; s2 = 0.f;
#pragma unroll
    for (int j = 0; j < 8; j++) { s1 += hv[j]; s2 += hv[j] * hv[j]; }
#pragma unroll
    for (int off = 32; off; off >>= 1) { s1 += __shfl_xor(s1, off); s2 += __shfl_xor(s2, off); }
    m = s1 * (1.f / DD);
    var = s2 * (1.f / DD) - m * m;
    rs = __builtin_amdgcn_rsqf(var + 1e-5f);
    float4 ca = *(const float4*)(cg + col), cbq = *(const float4*)(cg + col + 4);
    float4 da = *(const float4*)(cb + col), db = *(const float4*)(cb + col + 4);
    float cgv[8] = {ca.x, ca.y, ca.z, ca.w, cbq.x, cbq.y, cbq.z, cbq.w};
    float cbv[8] = {da.x, da.y, da.z, da.w, db.x, db.y, db.z, db.w};
    union { u16 q[8]; float4 f; } U;
#pragma unroll
    for (int j = 0; j < 8; j++) U.q[j] = f2b((hv[j] - m) * rs * cgv[j] + cbv[j]);
    *(float4*)(hn + row * DD + col) = U.f;
}

// ---------------------------------------------------------------------------
// bf16 MFMA GEMM: C[M,N] = A[M,K] * Bw[N,K]^T (+bias, epilogue variants)
// 128x128 tile, BK=32, 256 thr = 4 waves (2x2), global_load_lds staging
// EPI 0: +bias -> bf16 | EPI 1: +bias, exact gelu -> bf16 | EPI 2: +bias+resid -> f32
// ---------------------------------------------------------------------------
__device__ __forceinline__ void glds16(const u16* g, u16* l) {
    __builtin_amdgcn_global_load_lds((__attribute__((address_space(1))) const void*)g,
                                     (__attribute__((address_space(3))) void*)l, 16, 0, 0);
}

template <int EPI>
__global__ __launch_bounds__(256, 2)
void gemm_bt(const u16* __restrict__ A, const u16* __restrict__ Bw,
             const float* __restrict__ bias, const float* __restrict__ resid,
             void* __restrict__ Cout, int N, int K) {
    __shared__ u16 lA[128 * 32];
    __shared__ u16 lB[128 * 32];
    int tid = threadIdx.x, lane = tid & 63, wv = tid >> 6;
    int m0 = blockIdx.y * 128, n0 = blockIdx.x * 128;

    int c0 = wv * 2;
    int srow = c0 * 16 + (lane >> 2);
    int kk = (lane & 3) * 8;
    const u16* gA0 = A + ((size_t)(m0 + srow)) * K + kk;
    const u16* gA1 = gA0 + (size_t)16 * K;
    const u16* gB0 = Bw + ((size_t)(n0 + srow)) * K + kk;
    const u16* gB1 = gB0 + (size_t)16 * K;
    u16* sA0 = lA + c0 * 512;
    u16* sA1 = sA0 + 512;
    u16* sB0 = lB + c0 * 512;
    u16* sB1 = sB0 + 512;

    int wm = wv >> 1, wn = wv & 1;
    int quad = lane >> 4, l15 = lane & 15;
    int arow = (wm * 64 + l15) * 32 + quad * 8;
    int brow = (wn * 64 + l15) * 32 + quad * 8;

    f32x4 acc[4][4] = {};
    for (int k0 = 0; k0 < K; k0 += 32) {
        __syncthreads();
        glds16(gA0 + k0, sA0);
        glds16(gA1 + k0, sA1);
        glds16(gB0 + k0, sB0);
        glds16(gB1 + k0, sB1);
        __syncthreads();
        bf16x8 af[4], bfv[4];
#pragma unroll
        for (int mi = 0; mi < 4; mi++) af[mi] = *(const bf16x8*)&lA[arow + mi * 512];
#pragma unroll
        for (int ni = 0; ni < 4; ni++) bfv[ni] = *(const bf16x8*)&lB[brow + ni * 512];
#pragma unroll
        for (int mi = 0; mi < 4; mi++)
#pragma unroll
            for (int ni = 0; ni < 4; ni++)
                acc[mi][ni] = __builtin_amdgcn_mfma_f32_16x16x32_bf16(af[mi], bfv[ni], acc[mi][ni], 0, 0, 0);
    }

#pragma unroll
    for (int mi = 0; mi < 4; mi++) {
#pragma unroll
        for (int ni = 0; ni < 4; ni++) {
            int n = n0 + wn * 64 + ni * 16 + l15;
            float bs = bias[n];
#pragma unroll
            for (int r = 0; r < 4; r++) {
                int m = m0 + wm * 64 + mi * 16 + quad * 4 + r;
                float v = acc[mi][ni][r] + bs;
                size_t idx = (size_t)m * N + n;
                if (EPI == 0) {
                    ((u16*)Cout)[idx] = f2b(v);
                } else if (EPI == 1) {
                    float g = 0.5f * v * (1.f + erff(v * 0.70710678118654752f));
                    ((u16*)Cout)[idx] = f2b(g);
                } else {
                    ((float*)Cout)[idx] = v + resid[idx];
                }
            }
        }
    }
}

// ---------------------------------------------------------------------------
// Producer-consumer HGRN scan, v3: consumer has ZERO global memory ops.
// Block = 256 thr (4 waves), 64 chains (b, d0..d0+63), 64 blocks.
// Wave 0 (consumer): one ds_read_b128/step (prefetched), 6-op recurrence,
//   ds_write_b32 of raw fp32 s to a 2-slot LDS output ring.
// Waves 1..3 (producers, row-split t%3==wv-1):
//   - stage next chunk's proj (global loads stay in flight across barriers),
//   - precompute [c2, zz, ru2, om] -> f32x4, one ds_write_b128 per row,
//   - drain output ring from 2 chunks ago: ds_read, bf16-round, global store.
// barrier_nf(): s_waitcnt lgkmcnt(0); s_barrier  (NO vmcnt/expcnt drain).
// Schedule at iteration k (k = 0..NCHUNK+1, one barrier at top for all):
//   producers write operand slot k%3; consumer eats chunk k-1 from (k-1)%3,
//   writes ring slot (k-1)&1; producers store ring chunk k-2 from (k-2)&1.
// All hazards are >= 1 barrier apart.
// ---------------------------------------------------------------------------
#define SCH 32                       // timesteps per chunk
#define NCHUNK (TT / SCH)            // 128
#define SLOT_V (SCH * 64)            // 2048 f32x4 per slot (32 KB)

__global__ __launch_bounds__(256, 1)
void scan_pc(const u16* __restrict__ proj, const float* __restrict__ u,
             u16* __restrict__ sout) {
    __shared__ f32x4 lds[3 * SLOT_V];          // 96 KB operand ring
    __shared__ float oring[2 * SCH * 64];      // 16 KB output ring
    int tid = threadIdx.x, lane = tid & 63, wv = tid >> 6;
    int blk = blockIdx.x;
    int b = blk >> 3, d0 = (blk & 7) * 64;
    const float L2E = 1.4426950408889634f;

    if (wv == 0) {
        // ------------------------- consumer -------------------------
        float s = 0.f;
        for (int k = 0; k <= NCHUNK + 1; ++k) {
            barrier_nf();
            if (k < 1 || k > NCHUNK) continue;
            int c = k - 1;
            const f32x4* S = lds + (c % 3) * SLOT_V + lane;
            float* orp = oring + (c & 1) * (SCH * 64) + lane;
            f32x4 cur[8], nxt[8];
#pragma unroll
            for (int j = 0; j < 8; j++) cur[j] = S[j * 64];
#pragma unroll
            for (int sub = 0; sub < 4; ++sub) {
                if (sub < 3) {
                    const f32x4* Sp = S + (sub + 1) * 8 * 64;
#pragma unroll
                    for (int j = 0; j < 8; j++) nxt[j] = Sp[j * 64];
                }
                float* ops = orp + sub * 8 * 64;
#pragma unroll
                for (int j = 0; j < 8; j++) {
                    float c2 = cur[j][0], zz = cur[j][1], ru2 = cur[j][2], om = cur[j][3];
                    float e = __builtin_amdgcn_exp2f(fmaf(s, ru2, c2));
                    float a = fmaf(zz, s, om);
                    s = fmaf(-(om + om), __builtin_amdgcn_rcpf(e + 1.f), a);
                    ops[j * 64] = s;                         // ds_write_b32
                }
#pragma unroll
                for (int j = 0; j < 8; j++) cur[j] = nxt[j];
            }
        }
    } else {
        // ------------------------- producers (row-split) -------------------------
        int pw = wv - 1;                       // handles rows t == pw (mod 3)
        const int NR = (pw == 2) ? 10 : 11;    // rows per chunk
        const u16* base = proj + ((size_t)b * TT) * 1536 + d0 + lane;
        u16* so = sout + ((size_t)b * TT) * 512 + d0 + lane;
        float ru_c = (2.f * L2E) * u[d0 + lane];

        u16 sc[11], sz[11], sr[11];
#pragma unroll
        for (int i = 0; i < 11; i++) {
            if (i < NR) {
                const u16* q = base + (size_t)(3 * i + pw) * 1536;
                sc[i] = q[0]; sz[i] = q[512]; sr[i] = q[1024];
            }
        }
        for (int k = 0; k <= NCHUNK + 1; ++k) {
            barrier_nf();
            // drain output ring: chunk k-2
            if (k >= 2) {
                int c = k - 2;
                const float* orr = oring + (c & 1) * (SCH * 64) + lane;
                u16* sop = so + (size_t)c * SCH * 512;
#pragma unroll
                for (int i = 0; i < 11; i++) {
                    if (i < NR) {
                        int t = 3 * i + pw;
                        float sv_ = orr[t * 64];             // ds_read_b32
                        u32 uu;
                        __builtin_memcpy(&uu, &sv_, 4);
                        sop[(size_t)t * 512] = (u16)((uu + 0x8000u) >> 16);
                    }
                }
            }
            // stage operands: chunk k
            if (k < NCHUNK) {
                f32x4* Wp = lds + (k % 3) * SLOT_V + lane;
#pragma unroll
                for (int i = 0; i < 11; i++) {
                    if (i < NR) {
                        int t = 3 * i + pw;
                        float c = b2f(sc[i]), gz = b2f(sz[i]), gr = b2f(sr[i]);
                        float zz = __builtin_amdgcn_rcpf(1.f + __builtin_amdgcn_exp2f(-gz * L2E));
                        float rr = __builtin_amdgcn_rcpf(1.f + __builtin_amdgcn_exp2f(-gr * L2E));
                        f32x4 o = {(2.f * L2E) * c, zz, ru_c * rr, 1.f - zz};
                        Wp[t * 64] = o;                      // ds_write_b128
                    }
                }
                if (k + 1 < NCHUNK) {
                    const u16* nb = base + (size_t)(k + 1) * SCH * 1536;
#pragma unroll
                    for (int i = 0; i < 11; i++) {
                        if (i < NR) {
                            const u16* q = nb + (size_t)(3 * i + pw) * 1536;
                            sc[i] = q[0]; sz[i] = q[512]; sr[i] = q[1024];
                        }
                    }
                }
            }
        }
    }
}

// ---------------------------------------------------------------------------
// Fused: x2 = x + s + dwconv(h) ; hn2 = LN(x2)*g2+b2 (bf16). 1 wave/row.
// ---------------------------------------------------------------------------
__global__ __launch_bounds__(256)
void fuse_ln2(const float* __restrict__ x, const u16* __restrict__ hb,
              const u16* __restrict__ sv, const float* __restrict__ wt,
              const float* __restrict__ dwb, const float* __restrict__ g2,
              const float* __restrict__ b2, float* __restrict__ x2,
              u16* __restrict__ hn2) {
    int wv = threadIdx.x >> 6, lane = threadIdx.x & 63;
    size_t row = (size_t)blockIdx.x * 4 + wv;
    int b = (int)(row >> 12);
    int t = (int)(row & 4095);
    int col = lane * 8;

    float acc[8];
    {
        float4 d0 = *(const float4*)(dwb + col), d1 = *(const float4*)(dwb + col + 4);
        acc[0] = d0.x; acc[1] = d0.y; acc[2] = d0.z; acc[3] = d0.w;
        acc[4] = d1.x; acc[5] = d1.y; acc[6] = d1.z; acc[7] = d1.w;
    }
#pragma unroll
    for (int k = 0; k < 5; k++) {
        int tt = t + k - 2;
        if (tt >= 0 && tt < TT) {
            union { u16 q[8]; float4 f; } H;
            H.f = *(const float4*)(hb + (((size_t)b * TT) + tt) * DD + col);
            const float* wr = wt + k * DD + col;
            float4 w0 = *(const float4*)wr, w1 = *(const float4*)(wr + 4);
            float wv8[8] = {w0.x, w0.y, w0.z, w0.w, w1.x, w1.y, w1.z, w1.w};
#pragma unroll
            for (int j = 0; j < 8; j++) acc[j] = fmaf(b2f(H.q[j]), wv8[j], acc[j]);
        }
    }
    const float* xr = x + row * DD + col;
    float4 x0 = *(const float4*)xr, x1 = *(const float4*)(xr + 4);
    float xv[8] = {x0.x, x0.y, x0.z, x0.w, x1.x, x1.y, x1.z, x1.w};
    union { u16 q[8]; float4 f; } S;
    S.f = *(const float4*)(sv + row * DD + col);
    float v[8];
#pragma unroll
    for (int j = 0; j < 8; j++) v[j] = xv[j] + b2f(S.q[j]) + acc[j];
    {
        float4 o0 = {v[0], v[1], v[2], v[3]};
        float4 o1 = {v[4], v[5], v[6], v[7]};
        float* xo = x2 + row * DD + col;
        *(float4*)xo = o0;
        *(float4*)(xo + 4) = o1;
    }
    float s1 = 0.f, s2 = 0.f;
#pragma unroll
    for (int j = 0; j < 8; j++) { s1 += v[j]; s2 += v[j] * v[j]; }
#pragma unroll
    for (int off = 32; off; off >>= 1) { s1 += __shfl_xor(s1, off); s2 += __shfl_xor(s2, off); }
    float m = s1 * (1.f / DD);
    float var = s2 * (1.f / DD) - m * m;
    float rs = __builtin_amdgcn_rsqf(var + 1e-5f);
    float4 ga = *(const float4*)(g2 + col), gb = *(const float4*)(g2 + col + 4);
    float4 ba = *(const float4*)(b2 + col), bb = *(const float4*)(b2 + col + 4);
    float gv[8] = {ga.x, ga.y, ga.z, ga.w, gb.x, gb.y, gb.z, gb.w};
    float bv[8] = {ba.x, ba.y, ba.z, ba.w, bb.x, bb.y, bb.z, bb.w};
    union { u16 q[8]; float4 f; } U;
#pragma unroll
    for (int j = 0; j < 8; j++) U.q[j] = f2b((v[j] - m) * rs * gv[j] + bv[j]);
    *(float4*)(hn2 + row * DD + col) = U.f;
}

// ---------------------------------------------------------------------------
// Workspace layout (total ~227.6 MiB):
//   [0,32)MB    hb   (bf16 h)         dead after fuse_ln2
//   [32,64)MB   hn                    dead after gemm1
//   [64,96)MB   hn2
//   [96,128)MB  sv
//   [128,224)MB proj (bf16)           dead after scan
//   [128,192)MB x2   (fp32)           ALIASES proj (written after proj dead)
//   [0,64)MB    t1   (bf16)           ALIASES hb+hn (written after both dead)
//   [224MB,..)  wb (3.5MB bf16 weights) + wt (10KB)
// ---------------------------------------------------------------------------
extern "C" void kernel_launch(void* const* d_in, const int* in_sizes, int n_in,
                              void* d_out, int out_size, void* d_ws, size_t ws_size,
                              hipStream_t stream) {
    const float* x   = (const float*)d_in[0];
    const float* g1  = (const float*)d_in[1];
    const float* b1n = (const float*)d_in[2];
    const float* u   = (const float*)d_in[3];
    const float* Wi  = (const float*)d_in[4];
    const float* bi  = (const float*)d_in[5];
    const float* cg  = (const float*)d_in[6];
    const float* cbv = (const float*)d_in[7];
    const float* dww = (const float*)d_in[8];
    const float* dwb = (const float*)d_in[9];
    const float* g2  = (const float*)d_in[10];
    const float* b2n = (const float*)d_in[11];
    const float* W1  = (const float*)d_in[12];
    const float* b1m = (const float*)d_in[13];
    const float* W2  = (const float*)d_in[14];
    const float* b2m = (const float*)d_in[15];

    char* ws = (char*)d_ws;
    const size_t MB = 1024 * 1024;
    u16*   hb   = (u16*)(ws);                    // 32 MB
    u16*   hn   = (u16*)(ws + 32 * MB);          // 32 MB
    u16*   hn2  = (u16*)(ws + 64 * MB);          // 32 MB
    u16*   sv   = (u16*)(ws + 96 * MB);          // 32 MB
    u16*   proj = (u16*)(ws + 128 * MB);         // 96 MB
    float* x2   = (float*)(ws + 128 * MB);       // 64 MB, aliases proj
    u16*   t1   = (u16*)(ws);                    // 64 MB, aliases hb+hn
    u16*   wb   = (u16*)(ws + 224 * MB);         // 3.5 MB: Wi_b | W1_b | W2_b
    float* wt   = (float*)(ws + 224 * MB + (size_t)(1536 * 512 + 1024 * 512 + 512 * 1024) * 2);

    convert_kernel<<<1024, 256, 0, stream>>>(Wi, W1, W2, dww, wb, wt);
    ln_kernel<<<MM / 4, 256, 0, stream>>>(x, g1, b1n, cg, cbv, hb, hn);
    gemm_bt<0><<<dim3(12, MM / 128), 256, 0, stream>>>(hn, wb, bi, nullptr, proj, 1536, 512);
    scan_pc<<<64, 256, 0, stream>>>(proj, u, sv);
    fuse_ln2<<<MM / 4, 256, 0, stream>>>(x, hb, sv, wt, dwb, g2, b2n, x2, hn2);
    gemm_bt<1><<<dim3(8, MM / 128), 256, 0, stream>>>(hn2, wb + 1536 * 512, b1m, nullptr, t1, 1024, 512);
    gemm_bt<2><<<dim3(4, MM / 128), 256, 0, stream>>>(t1, wb + 1536 * 512 + 1024 * 512, b2m, x2, d_out, 512, 1024);
}

// Round 6
// 559.016 us; speedup vs baseline: 1.0988x; 1.0988x over previous
//
#include <hip/hip_runtime.h>
#include <cstdint>
#include <cmath>

typedef unsigned short u16;
typedef unsigned int u32;
typedef __attribute__((ext_vector_type(8))) short bf16x8;
typedef __attribute__((ext_vector_type(4))) float f32x4;

#define TT 4096
#define DD 512
#define MM (8 * 4096)   // B*T rows

__device__ __forceinline__ float b2f(u16 v) {
    u32 u = ((u32)v) << 16;
    float f;
    __builtin_memcpy(&f, &u, 4);
    return f;
}
__device__ __forceinline__ u16 f2b(float f) {
    u32 u;
    __builtin_memcpy(&u, &f, 4);
    u32 r = (u + 0x7fffu + ((u >> 16) & 1u)) >> 16;  // RNE
    return (u16)r;
}

// ---------------------------------------------------------------------------
// Weight conversion: Wi,W1,W2 -> bf16 (concat), dw_w [512,1,5] -> wt [5][512]
// ---------------------------------------------------------------------------
__global__ void convert_kernel(const float* __restrict__ Wi, const float* __restrict__ W1,
                               const float* __restrict__ W2, const float* __restrict__ dw,
                               u16* __restrict__ wb, float* __restrict__ wt) {
    int i = blockIdx.x * blockDim.x + threadIdx.x;
    const int n0 = 1536 * 512, n1 = n0 + 1024 * 512, n2 = n1 + 512 * 1024;
    for (int idx = i; idx < n2; idx += gridDim.x * blockDim.x) {
        float v;
        if (idx < n0) v = Wi[idx];
        else if (idx < n1) v = W1[idx - n0];
        else v = W2[idx - n1];
        wb[idx] = f2b(v);
    }
    if (i < 5 * 512) {
        int k = i >> 9, d = i & 511;
        wt[i] = dw[d * 5 + k];
    }
}

// ---------------------------------------------------------------------------
// Fused LN1 + cell-LN: h = LN(x)*g1+b1 (stored bf16), hn = LN(h)*cg+cb (bf16)
// 1 wave per row (512 cols, 8/lane)
// ---------------------------------------------------------------------------
__global__ __launch_bounds__(256)
void ln_kernel(const float* __restrict__ x, const float* __restrict__ g1,
               const float* __restrict__ b1, const float* __restrict__ cg,
               const float* __restrict__ cb, u16* __restrict__ hb,
               u16* __restrict__ hn) {
    int wv = threadIdx.x >> 6, lane = threadIdx.x & 63;
    size_t row = (size_t)blockIdx.x * 4 + wv;
    int col = lane * 8;
    const float* xr = x + row * DD + col;
    float v[8];
    {
        float4 a = *(const float4*)xr;
        float4 b = *(const float4*)(xr + 4);
        v[0] = a.x; v[1] = a.y; v[2] = a.z; v[3] = a.w;
        v[4] = b.x; v[5] = b.y; v[6] = b.z; v[7] = b.w;
    }
    float s1 = 0.f, s2 = 0.f;
#pragma unroll
    for (int j = 0; j < 8; j++) { s1 += v[j]; s2 += v[j] * v[j]; }
#pragma unroll
    for (int off = 32; off; off >>= 1) { s1 += __shfl_xor(s1, off); s2 += __shfl_xor(s2, off); }
    float m = s1 * (1.f / DD);
    float var = s2 * (1.f / DD) - m * m;
    float rs = __builtin_amdgcn_rsqf(var + 1e-5f);

    float4 ga = *(const float4*)(g1 + col), gb = *(const float4*)(g1 + col + 4);
    float4 ba = *(const float4*)(b1 + col), bb = *(const float4*)(b1 + col + 4);
    float gv[8] = {ga.x, ga.y, ga.z, ga.w, gb.x, gb.y, gb.z, gb.w};
    float bv[8] = {ba.x, ba.y, ba.z, ba.w, bb.x, bb.y, bb.z, bb.w};
    float hv[8];
#pragma unroll
    for (int j = 0; j < 8; j++) hv[j] = (v[j] - m) * rs * gv[j] + bv[j];
    {
        union { u16 q[8]; float4 f; } H;
#pragma unroll
        for (int j = 0; j < 8; j++) H.q[j] = f2b(hv[j]);
        *(float4*)(hb + row * DD + col) = H.f;
    }
    // second LN over h (fp32 hv)
    s1 = 0.f; s2 = 0.f;
#pragma unroll
    for (int j = 0; j < 8; j++) { s1 += hv[j]; s2 += hv[j] * hv[j]; }
#pragma unroll
    for (int off = 32; off; off >>= 1) { s1 += __shfl_xor(s1, off); s2 += __shfl_xor(s2, off); }
    m = s1 * (1.f / DD);
    var = s2 * (1.f / DD) - m * m;
    rs = __builtin_amdgcn_rsqf(var + 1e-5f);
    float4 ca = *(const float4*)(cg + col), cbq = *(const float4*)(cg + col + 4);
    float4 da = *(const float4*)(cb + col), db = *(const float4*)(cb + col + 4);
    float cgv[8] = {ca.x, ca.y, ca.z, ca.w, cbq.x, cbq.y, cbq.z, cbq.w};
    float cbv[8] = {da.x, da.y, da.z, da.w, db.x, db.y, db.z, db.w};
    union { u16 q[8]; float4 f; } U;
#pragma unroll
    for (int j = 0; j < 8; j++) U.q[j] = f2b((hv[j] - m) * rs * cgv[j] + cbv[j]);
    *(float4*)(hn + row * DD + col) = U.f;
}

// ---------------------------------------------------------------------------
// bf16 MFMA GEMM v2: C[M,N] = A[M,K] * Bw[N,K]^T (+bias, epilogue variants)
// 128x128 tile, BK=64 (2 x 32-wide LDS panels), 256 thr = 4 waves (2x2),
// global_load_lds staging, 3 blocks/CU target.
// EPI 0: +bias -> bf16 | EPI 1: +bias, exact gelu -> bf16 | EPI 2: +bias+resid -> f32
// ---------------------------------------------------------------------------
__device__ __forceinline__ void glds16(const u16* g, u16* l) {
    __builtin_amdgcn_global_load_lds((__attribute__((address_space(1))) const void*)g,
                                     (__attribute__((address_space(3))) void*)l, 16, 0, 0);
}

template <int EPI>
__global__ __launch_bounds__(256, 3)
void gemm_bt(const u16* __restrict__ A, const u16* __restrict__ Bw,
             const float* __restrict__ bias, const float* __restrict__ resid,
             void* __restrict__ Cout, int N, int K) {
    __shared__ u16 lA[2][128 * 32];
    __shared__ u16 lB[2][128 * 32];
    int tid = threadIdx.x, lane = tid & 63, wv = tid >> 6;
    int m0 = blockIdx.y * 128, n0 = blockIdx.x * 128;

    // staging: wave wv covers rows [wv*32, wv*32+32) of each panel.
    // per glds16: 64 lanes x 16B = 16 rows x 32 cols (lane>>2 row, (lane&3)*8 col)
    int c0 = wv * 2;
    int srow = c0 * 16 + (lane >> 2);
    int kk = (lane & 3) * 8;
    const u16* gA0 = A + ((size_t)(m0 + srow)) * K + kk;
    const u16* gA1 = gA0 + (size_t)16 * K;
    const u16* gB0 = Bw + ((size_t)(n0 + srow)) * K + kk;
    const u16* gB1 = gB0 + (size_t)16 * K;
    int sOff0 = c0 * 512, sOff1 = sOff0 + 512;

    int wm = wv >> 1, wn = wv & 1;
    int quad = lane >> 4, l15 = lane & 15;
    int arow = (wm * 64 + l15) * 32 + quad * 8;
    int brow = (wn * 64 + l15) * 32 + quad * 8;

    f32x4 acc[4][4] = {};
    for (int k0 = 0; k0 < K; k0 += 64) {
        __syncthreads();
        glds16(gA0 + k0,      &lA[0][sOff0]);
        glds16(gA1 + k0,      &lA[0][sOff1]);
        glds16(gA0 + k0 + 32, &lA[1][sOff0]);
        glds16(gA1 + k0 + 32, &lA[1][sOff1]);
        glds16(gB0 + k0,      &lB[0][sOff0]);
        glds16(gB1 + k0,      &lB[0][sOff1]);
        glds16(gB0 + k0 + 32, &lB[1][sOff0]);
        glds16(gB1 + k0 + 32, &lB[1][sOff1]);
        __syncthreads();
#pragma unroll
        for (int p = 0; p < 2; p++) {
            bf16x8 af[4], bfv[4];
#pragma unroll
            for (int mi = 0; mi < 4; mi++) af[mi] = *(const bf16x8*)&lA[p][arow + mi * 512];
#pragma unroll
            for (int ni = 0; ni < 4; ni++) bfv[ni] = *(const bf16x8*)&lB[p][brow + ni * 512];
#pragma unroll
            for (int mi = 0; mi < 4; mi++)
#pragma unroll
                for (int ni = 0; ni < 4; ni++)
                    acc[mi][ni] = __builtin_amdgcn_mfma_f32_16x16x32_bf16(af[mi], bfv[ni], acc[mi][ni], 0, 0, 0);
        }
    }

#pragma unroll
    for (int mi = 0; mi < 4; mi++) {
#pragma unroll
        for (int ni = 0; ni < 4; ni++) {
            int n = n0 + wn * 64 + ni * 16 + l15;
            float bs = bias[n];
#pragma unroll
            for (int r = 0; r < 4; r++) {
                int m = m0 + wm * 64 + mi * 16 + quad * 4 + r;
                float v = acc[mi][ni][r] + bs;
                size_t idx = (size_t)m * N + n;
                if (EPI == 0) {
                    ((u16*)Cout)[idx] = f2b(v);
                } else if (EPI == 1) {
                    float g = 0.5f * v * (1.f + erff(v * 0.70710678118654752f));
                    ((u16*)Cout)[idx] = f2b(g);
                } else {
                    ((float*)Cout)[idx] = v + resid[idx];
                }
            }
        }
    }
}

// ---------------------------------------------------------------------------
// Producer-consumer HGRN scan (round-3 structure — best measured: 162 us).
// Block = 256 thr (4 waves), handles 64 chains (b, d0..d0+63), 64 blocks.
// Wave 0: consumer — runs the sequential recurrence from LDS-staged operands.
// Waves 1/2/3: producers for planes cand/gz/gr — coalesced u32 loads one
// chunk (32 t) ahead, precompute c2 = 2*log2e*c | zt = sigmoid(gz) |
// ru2 = 2*log2e*u*sigmoid(gr), stage fp32 into triple-buffered LDS ring.
// One barrier per chunk; mod-3 slots make write/read epochs disjoint.
// ---------------------------------------------------------------------------
#define SCH 32                      // timesteps per chunk
#define NCHUNK (TT / SCH)           // 128
#define PLANE_F (SCH * 64)          // 2048 floats per plane per slot
#define SLOT_F (3 * PLANE_F)        // 6144 floats per slot

__global__ __launch_bounds__(256, 1)
void scan_pc(const u16* __restrict__ proj, const float* __restrict__ u,
             u16* __restrict__ sout) {
    __shared__ float lds[3 * SLOT_F];   // 72 KB
    int tid = threadIdx.x, lane = tid & 63, wv = tid >> 6;
    int blk = blockIdx.x;
    int b = blk >> 3, d0 = (blk & 7) * 64;
    const float L2E = 1.4426950408889634f;

    if (wv == 0) {
        // ------------------------- consumer -------------------------
        float s = 0.f;
        u16* so = sout + ((size_t)b * TT) * 512 + d0 + lane;
        for (int k = 0; k < NCHUNK + 1; ++k) {
            __syncthreads();
            if (k == 0) continue;
            int c = k - 1;
            const float* S = lds + (c % 3) * SLOT_F;
            const float* Pc = S;
            const float* Pz = S + PLANE_F;
            const float* Pr = S + 2 * PLANE_F;
            u16* sop = so + (size_t)c * SCH * 512;
            float cc[8], zz[8], rr[8];
#pragma unroll
            for (int j = 0; j < 8; j++) {
                cc[j] = Pc[j * 64 + lane]; zz[j] = Pz[j * 64 + lane]; rr[j] = Pr[j * 64 + lane];
            }
#pragma unroll
            for (int sub = 0; sub < 4; ++sub) {
                float nc[8], nz[8], nr[8];
                if (sub < 3) {
                    int t = (sub + 1) * 8;
#pragma unroll
                    for (int j = 0; j < 8; j++) {
                        nc[j] = Pc[(t + j) * 64 + lane];
                        nz[j] = Pz[(t + j) * 64 + lane];
                        nr[j] = Pr[(t + j) * 64 + lane];
                    }
                }
#pragma unroll
                for (int j = 0; j < 8; j++) {
                    float om = 1.f - zz[j];
                    float e = __builtin_amdgcn_exp2f(fmaf(s, rr[j], cc[j]));
                    float a = fmaf(zz[j], s, om);
                    s = fmaf(-(om + om), __builtin_amdgcn_rcpf(e + 1.f), a);
                    sop[(sub * 8 + j) * 512] = f2b(s);
                }
#pragma unroll
                for (int j = 0; j < 8; j++) { cc[j] = nc[j]; zz[j] = nz[j]; rr[j] = nr[j]; }
            }
        }
    } else {
        // ------------------------- producers -------------------------
        int plane = wv - 1;                       // 0=cand 1=gz 2=gr
        int hl = lane & 31, rsel = lane >> 5;     // lane -> (dword, row parity)
        const u16* base = proj + ((size_t)b * TT) * 1536 + plane * 512 + d0 + 2 * hl;
        float ud0 = 0.f, ud1 = 0.f;
        if (plane == 2) { ud0 = u[d0 + 2 * hl]; ud1 = u[d0 + 2 * hl + 1]; }

        u32 stage[16];
#pragma unroll
        for (int i = 0; i < 16; i++)
            stage[i] = *(const u32*)(base + (size_t)(2 * i + rsel) * 1536);

        for (int k = 0; k < NCHUNK + 1; ++k) {
            if (k < NCHUNK) {
                float* Wp = lds + (k % 3) * SLOT_F + plane * PLANE_F + hl * 2;
#pragma unroll
                for (int i = 0; i < 16; i++) {
                    u32 v = stage[i];
                    float lo = b2f((u16)(v & 0xffffu));
                    float hi = b2f((u16)(v >> 16));
                    float o0, o1;
                    if (plane == 0) {
                        o0 = (2.f * L2E) * lo; o1 = (2.f * L2E) * hi;
                    } else {
                        float s0 = __builtin_amdgcn_rcpf(1.f + __builtin_amdgcn_exp2f(-lo * L2E));
                        float s1 = __builtin_amdgcn_rcpf(1.f + __builtin_amdgcn_exp2f(-hi * L2E));
                        if (plane == 1) { o0 = s0; o1 = s1; }
                        else { o0 = (2.f * L2E) * ud0 * s0; o1 = (2.f * L2E) * ud1 * s1; }
                    }
                    int row = 2 * i + rsel;
                    float2 pr = {o0, o1};
                    *(float2*)(Wp + row * 64) = pr;
                }
                if (k + 1 < NCHUNK) {
                    const u16* nb = base + (size_t)(k + 1) * SCH * 1536;
#pragma unroll
                    for (int i = 0; i < 16; i++)
                        stage[i] = *(const u32*)(nb + (size_t)(2 * i + rsel) * 1536);
                }
            }
            __syncthreads();
        }
    }
}

// ---------------------------------------------------------------------------
// Fused: x2 = x + s + dwconv(h) ; hn2 = LN(x2)*g2+b2 (bf16). 1 wave/row.
// ---------------------------------------------------------------------------
__global__ __launch_bounds__(256)
void fuse_ln2(const float* __restrict__ x, const u16* __restrict__ hb,
              const u16* __restrict__ sv, const float* __restrict__ wt,
              const float* __restrict__ dwb, const float* __restrict__ g2,
              const float* __restrict__ b2, float* __restrict__ x2,
              u16* __restrict__ hn2) {
    int wv = threadIdx.x >> 6, lane = threadIdx.x & 63;
    size_t row = (size_t)blockIdx.x * 4 + wv;
    int b = (int)(row >> 12);
    int t = (int)(row & 4095);
    int col = lane * 8;

    float acc[8];
    {
        float4 d0 = *(const float4*)(dwb + col), d1 = *(const float4*)(dwb + col + 4);
        acc[0] = d0.x; acc[1] = d0.y; acc[2] = d0.z; acc[3] = d0.w;
        acc[4] = d1.x; acc[5] = d1.y; acc[6] = d1.z; acc[7] = d1.w;
    }
#pragma unroll
    for (int k = 0; k < 5; k++) {
        int tt = t + k - 2;
        if (tt >= 0 && tt < TT) {
            union { u16 q[8]; float4 f; } H;
            H.f = *(const float4*)(hb + (((size_t)b * TT) + tt) * DD + col);
            const float* wr = wt + k * DD + col;
            float4 w0 = *(const float4*)wr, w1 = *(const float4*)(wr + 4);
            float wv8[8] = {w0.x, w0.y, w0.z, w0.w, w1.x, w1.y, w1.z, w1.w};
#pragma unroll
            for (int j = 0; j < 8; j++) acc[j] = fmaf(b2f(H.q[j]), wv8[j], acc[j]);
        }
    }
    const float* xr = x + row * DD + col;
    float4 x0 = *(const float4*)xr, x1 = *(const float4*)(xr + 4);
    float xv[8] = {x0.x, x0.y, x0.z, x0.w, x1.x, x1.y, x1.z, x1.w};
    union { u16 q[8]; float4 f; } S;
    S.f = *(const float4*)(sv + row * DD + col);
    float v[8];
#pragma unroll
    for (int j = 0; j < 8; j++) v[j] = xv[j] + b2f(S.q[j]) + acc[j];
    {
        float4 o0 = {v[0], v[1], v[2], v[3]};
        float4 o1 = {v[4], v[5], v[6], v[7]};
        float* xo = x2 + row * DD + col;
        *(float4*)xo = o0;
        *(float4*)(xo + 4) = o1;
    }
    float s1 = 0.f, s2 = 0.f;
#pragma unroll
    for (int j = 0; j < 8; j++) { s1 += v[j]; s2 += v[j] * v[j]; }
#pragma unroll
    for (int off = 32; off; off >>= 1) { s1 += __shfl_xor(s1, off); s2 += __shfl_xor(s2, off); }
    float m = s1 * (1.f / DD);
    float var = s2 * (1.f / DD) - m * m;
    float rs = __builtin_amdgcn_rsqf(var + 1e-5f);
    float4 ga = *(const float4*)(g2 + col), gb = *(const float4*)(g2 + col + 4);
    float4 ba = *(const float4*)(b2 + col), bb = *(const float4*)(b2 + col + 4);
    float gv[8] = {ga.x, ga.y, ga.z, ga.w, gb.x, gb.y, gb.z, gb.w};
    float bv[8] = {ba.x, ba.y, ba.z, ba.w, bb.x, bb.y, bb.z, bb.w};
    union { u16 q[8]; float4 f; } U;
#pragma unroll
    for (int j = 0; j < 8; j++) U.q[j] = f2b((v[j] - m) * rs * gv[j] + bv[j]);
    *(float4*)(hn2 + row * DD + col) = U.f;
}

// ---------------------------------------------------------------------------
// Workspace layout (total ~227.6 MiB):
//   [0,32)MB    hb   (bf16 h)         dead after fuse_ln2
//   [32,64)MB   hn                    dead after gemm1
//   [64,96)MB   hn2
//   [96,128)MB  sv
//   [128,224)MB proj (bf16)           dead after scan
//   [128,192)MB x2   (fp32)           ALIASES proj (written after proj dead)
//   [0,64)MB    t1   (bf16)           ALIASES hb+hn (written after both dead)
//   [224MB,..)  wb (3.5MB bf16 weights) + wt (10KB)
// ---------------------------------------------------------------------------
extern "C" void kernel_launch(void* const* d_in, const int* in_sizes, int n_in,
                              void* d_out, int out_size, void* d_ws, size_t ws_size,
                              hipStream_t stream) {
    const float* x   = (const float*)d_in[0];
    const float* g1  = (const float*)d_in[1];
    const float* b1n = (const float*)d_in[2];
    const float* u   = (const float*)d_in[3];
    const float* Wi  = (const float*)d_in[4];
    const float* bi  = (const float*)d_in[5];
    const float* cg  = (const float*)d_in[6];
    const float* cbv = (const float*)d_in[7];
    const float* dww = (const float*)d_in[8];
    const float* dwb = (const float*)d_in[9];
    const float* g2  = (const float*)d_in[10];
    const float* b2n = (const float*)d_in[11];
    const float* W1  = (const float*)d_in[12];
    const float* b1m = (const float*)d_in[13];
    const float* W2  = (const float*)d_in[14];
    const float* b2m = (const float*)d_in[15];

    char* ws = (char*)d_ws;
    const size_t MB = 1024 * 1024;
    u16*   hb   = (u16*)(ws);                    // 32 MB
    u16*   hn   = (u16*)(ws + 32 * MB);          // 32 MB
    u16*   hn2  = (u16*)(ws + 64 * MB);          // 32 MB
    u16*   sv   = (u16*)(ws + 96 * MB);          // 32 MB
    u16*   proj = (u16*)(ws + 128 * MB);         // 96 MB
    float* x2   = (float*)(ws + 128 * MB);       // 64 MB, aliases proj
    u16*   t1   = (u16*)(ws);                    // 64 MB, aliases hb+hn
    u16*   wb   = (u16*)(ws + 224 * MB);         // 3.5 MB: Wi_b | W1_b | W2_b
    float* wt   = (float*)(ws + 224 * MB + (size_t)(1536 * 512 + 1024 * 512 + 512 * 1024) * 2);

    convert_kernel<<<1024, 256, 0, stream>>>(Wi, W1, W2, dww, wb, wt);
    ln_kernel<<<MM / 4, 256, 0, stream>>>(x, g1, b1n, cg, cbv, hb, hn);
    gemm_bt<0><<<dim3(12, MM / 128), 256, 0, stream>>>(hn, wb, bi, nullptr, proj, 1536, 512);
    scan_pc<<<64, 256, 0, stream>>>(proj, u, sv);
    fuse_ln2<<<MM / 4, 256, 0, stream>>>(x, hb, sv, wt, dwb, g2, b2n, x2, hn2);
    gemm_bt<1><<<dim3(8, MM / 128), 256, 0, stream>>>(hn2, wb + 1536 * 512, b1m, nullptr, t1, 1024, 512);
    gemm_bt<2><<<dim3(4, MM / 128), 256, 0, stream>>>(t1, wb + 1536 * 512 + 1024 * 512, b2m, x2, d_out, 512, 1024);
}